// Round 10
// baseline (404.075 us; speedup 1.0000x reference)
//
#include <hip/hip_runtime.h>
#include <hip/hip_cooperative_groups.h>

namespace cg = cooperative_groups;

typedef unsigned short u16;
typedef __bf16 bf16;
typedef bf16 bf16x8 __attribute__((ext_vector_type(8)));
typedef float f32x4 __attribute__((ext_vector_type(4)));

#define S 2048
#define D 64
#define BATCH 4
#define SCL 0.022097086912079612f  /* 1/sqrt(2048) */
#define NBLK 512

__device__ __forceinline__ u16 f2bf(float f) {
  union { float f; unsigned u; } v; v.f = f;
  return (u16)((v.u + 0x7FFFu + ((v.u >> 16) & 1u)) >> 16);
}

__device__ __forceinline__ void gld16(const u16* g, u16* l) {
  __builtin_amdgcn_global_load_lds(
      (const __attribute__((address_space(1))) unsigned int*)(const void*)g,
      (__attribute__((address_space(3))) unsigned int*)(void*)l, 16, 0, 0);
}

// Single cooperative kernel; phases are R9's kernels verbatim, glued by
// grid.sync(). 512 blocks x 256 threads; LDS 48KB -> >=2 blocks/CU resident.
__global__ __launch_bounds__(256, 2) void k_fused(
    const float* __restrict__ x, const float* __restrict__ wq,
    const float* __restrict__ wv,
    u16* __restrict__ wqp, u16* __restrict__ wvb,
    u16* __restrict__ xb, u16* __restrict__ xTb,
    u16* __restrict__ Qb, u16* __restrict__ VTb,
    float* __restrict__ rzbuf, float* __restrict__ out) {
  __shared__ __align__(16) unsigned char smem[49152];
  cg::grid_group grid = cg::this_grid();
  const int bid = blockIdx.x;
  const int t = threadIdx.x;
  const int w = t >> 6, l = t & 63;
  const int lr = l & 15, lg = l >> 4;

  // ================= P0: pre (R9 k_pre, grid-stride) =================
  for (int bx = bid; bx < 3200; bx += NBLK) {
    if (bx < 512) {                        // W' suffix scan (vectorized)
      int m = bx * 4 + w;
      const float* row = wq + (size_t)m * S;
      u16* orow = wqp + (size_t)m * S;
      float4 f[8];
#pragma unroll
      for (int c = 0; c < 8; ++c) f[c] = *(const float4*)(row + c * 256 + l * 4);
#pragma unroll
      for (int c = 0; c < 8; ++c) {
        int base = c * 256 + l * 4;
        f[c].x /= (float)(base + 1); f[c].y /= (float)(base + 2);
        f[c].z /= (float)(base + 3); f[c].w /= (float)(base + 4);
      }
      float carry = 0.f;
#pragma unroll
      for (int c = 7; c >= 0; --c) {
        float4 v = f[c];
        float sl = v.x + v.y + v.z + v.w;
        float s = sl;
#pragma unroll
        for (int off = 1; off < 64; off <<= 1) {
          float o = __shfl_down(s, off);
          s += (l + off < 64) ? o : 0.f;
        }
        float tot = __shfl(s, 0);
        float excl = s - sl;
        float s3 = v.w, s2 = v.z + s3, s1 = v.y + s2, s0 = v.x + s1;
        union { u16 q[4]; ushort4 u4; } o;
        o.q[0] = f2bf(carry + excl + s0);
        o.q[1] = f2bf(carry + excl + s1);
        o.q[2] = f2bf(carry + excl + s2);
        o.q[3] = f2bf(carry + excl + s3);
        *(ushort4*)(orow + c * 256 + l * 4) = o.u4;
        carry += tot;
      }
    } else if (bx < 2560) {                // W_V convert
      size_t idx = ((size_t)(bx - 512) * 256 + t) * 8;
      const float* src = wv + idx;
      float4 a = *(const float4*)src;
      float4 b = *(const float4*)(src + 4);
      union { u16 s[8]; uint4 v; } u;
      u.s[0]=f2bf(a.x); u.s[1]=f2bf(a.y); u.s[2]=f2bf(a.z); u.s[3]=f2bf(a.w);
      u.s[4]=f2bf(b.x); u.s[5]=f2bf(b.y); u.s[6]=f2bf(b.z); u.s[7]=f2bf(b.w);
      *(uint4*)(wvb + idx) = u.v;
    } else if (bx < 2688) {                // x convert + transpose
      int job = (bx - 2560) * 4 + w;
      int chunk = job >> 2, b = job & 3, d = l;
      const float* xp = x + ((size_t)b * S + (size_t)chunk * 16) * D + d;
#pragma unroll
      for (int s = 0; s < 16; ++s) {
        float v = xp[(size_t)s * D];
        int sg = chunk * 16 + s;
        u16 h = f2bf(v);
        xb[((size_t)b * S + sg) * D + d] = h;
        xTb[((size_t)b * D + d) * S + sg] = h;
      }
    } else {                               // zero d_out
      size_t i = (((size_t)(bx - 2688) * 256) + t) * 4;
      *(float4*)(out + i) = make_float4(0.f, 0.f, 0.f, 0.f);
    }
  }
  __threadfence();
  grid.sync();

  // ================= P1: wg (R9 k_wg; waves 0-1 active, barriers hoisted) ====
  {
    u16* Ab = (u16*)smem;             // [2][64*128] = 32 KB
    u16* Bb = (u16*)(smem + 32768);   // [2][32*128] = 16 KB
    const int bx = bid;               // nt*64 + mt*2 + mat
    const int nt = bx >> 6, mm = bx & 63, mt = mm >> 1, mat = mm & 1;
    const bool act = (t < 128);
    const u16* A = (mat ? wvb : wqp) + (size_t)(mt * 64) * S;
    const u16* BT = xTb + (size_t)(nt * 32) * S;
    const int rA = t >> 4;            // active: 0..7
    const int sb = t & 15;            // 16B slot within 256B row
    const int swz = ((sb & 8) | ((sb & 7) ^ (rA & 7))) * 8;
    const u16* Ag = A + (size_t)rA * S + swz;
    const u16* Bg = BT + (size_t)rA * S + swz;
    f32x4 acc[2][2] = {};
    auto stage = [&](int buf, int kt) {
#pragma unroll
      for (int i = 0; i < 8; ++i)
        gld16(Ag + kt * 128 + (size_t)i * 8 * S, Ab + buf * 8192 + i * 1024 + t * 8);
#pragma unroll
      for (int i = 0; i < 4; ++i)
        gld16(Bg + kt * 128 + (size_t)i * 8 * S, Bb + buf * 4096 + i * 1024 + t * 8);
    };
    if (act) stage(0, 0);
    __syncthreads();
    int buf = 0;
    for (int kt = 0; kt < 16; ++kt) {
      if (act) {
        if (kt < 15) stage(buf ^ 1, kt + 1);
        bf16x8 af[2][4], bfv[2][4];
#pragma unroll
        for (int mf = 0; mf < 2; ++mf)
#pragma unroll
          for (int ks = 0; ks < 4; ++ks) {
            int row = w * 32 + mf * 16 + lr;
            int s = ks * 4 + lg;
            int col = ((s & 8) | ((s & 7) ^ (lr & 7))) * 8;
            af[mf][ks] = *(const bf16x8*)&Ab[buf * 8192 + row * 128 + col];
          }
#pragma unroll
        for (int nf = 0; nf < 2; ++nf)
#pragma unroll
          for (int ks = 0; ks < 4; ++ks) {
            int row = nf * 16 + lr;
            int s = ks * 4 + lg;
            int col = ((s & 8) | ((s & 7) ^ (lr & 7))) * 8;
            bfv[nf][ks] = *(const bf16x8*)&Bb[buf * 4096 + row * 128 + col];
          }
#pragma unroll
        for (int ks = 0; ks < 4; ++ks)
#pragma unroll
          for (int mf = 0; mf < 2; ++mf)
#pragma unroll
            for (int nf = 0; nf < 2; ++nf)
              acc[mf][nf] = __builtin_amdgcn_mfma_f32_16x16x32_bf16(af[mf][ks], bfv[nf][ks], acc[mf][nf], 0, 0, 0);
      }
      __syncthreads();
      buf ^= 1;
    }
    if (act) {
#pragma unroll
      for (int mf = 0; mf < 2; ++mf) {
        int mbase = mt * 64 + w * 32 + mf * 16 + lg * 4;
#pragma unroll
        for (int nf = 0; nf < 2; ++nf) {
          int n = nt * 32 + nf * 16 + lr;
          int b = n >> 6, d = n & 63;
          if (mat == 0) {
#pragma unroll
            for (int r = 0; r < 4; ++r)
              Qb[((size_t)b * S + mbase + r) * D + d] = f2bf(acc[mf][nf][r]);
          } else {
            union { u16 s2[4]; ushort4 v; } u;
#pragma unroll
            for (int r = 0; r < 4; ++r) u.s2[r] = f2bf(acc[mf][nf][r]);
            *(ushort4*)&VTb[((size_t)b * D + d) * S + mbase] = u.v;
          }
        }
      }
    }
  }
  __threadfence();
  grid.sync();

  // ================= P2: stats (R9 k_stats) =================
  {
    float (*zs)[16] = (float(*)[16])smem;
    int jg = bid >> 2, b = bid & 3;
    int j0 = jg * 16;
    const u16* xbase = xb + (size_t)b * S * D;
    const u16* qbase = Qb + (size_t)b * S * D;
    bf16x8 xa0 = *(const bf16x8*)(xbase + (size_t)(j0 + lr) * D + lg * 8);
    bf16x8 xa1 = *(const bf16x8*)(xbase + (size_t)(j0 + lr) * D + 32 + lg * 8);
    float z[4] = {0.f, 0.f, 0.f, 0.f};
    for (int i16 = j0 + w * 16; i16 < S; i16 += 64) {
      bf16x8 q0 = *(const bf16x8*)(qbase + (size_t)(i16 + lr) * D + lg * 8);
      bf16x8 q1 = *(const bf16x8*)(qbase + (size_t)(i16 + lr) * D + 32 + lg * 8);
      f32x4 c = {};
      c = __builtin_amdgcn_mfma_f32_16x16x32_bf16(xa0, q0, c, 0, 0, 0);
      c = __builtin_amdgcn_mfma_f32_16x16x32_bf16(xa1, q1, c, 0, 0, 0);
      int i = i16 + lr;
#pragma unroll
      for (int r = 0; r < 4; ++r) {
        int j = j0 + lg * 4 + r;
        float sc = c[r];
        z[r] += (i >= j && sc > 1.0f) ? __expf(sc * SCL) : 0.f;
      }
    }
#pragma unroll
    for (int r = 0; r < 4; ++r) {
      z[r] += __shfl_xor(z[r], 1);
      z[r] += __shfl_xor(z[r], 2);
      z[r] += __shfl_xor(z[r], 4);
      z[r] += __shfl_xor(z[r], 8);
    }
    if (lr == 0) {
#pragma unroll
      for (int r = 0; r < 4; ++r) zs[w][lg * 4 + r] = z[r];
    }
    __syncthreads();
    if (t < 16) {
      float zf = zs[0][t] + zs[1][t] + zs[2][t] + zs[3][t];
      rzbuf[(size_t)b * S + j0 + t] = 1.0f / zf;
    }
  }
  __threadfence();
  grid.sync();

  // ================= P3: out (R9 k_out, grid-stride heavy-first) =============
  for (int jj = bid; jj < 576; jj += NBLK) {
    u16 (*Plds)[16][72] = (u16(*)[16][72])smem;
    int b = jj & 3;
    int obx = 143 - (jj >> 2);   // heavy-first
    int it = 0, jc = 0, base = 0;
    for (int tt = 0; tt < 32; ++tt) {
      int nc = (tt + 4) >> 2;
      if (obx < base + nc) { it = tt; jc = obx - base; break; }
      base += nc;
    }
    int i0 = it * 64 + w * 16;
    const u16* xbase = xb + (size_t)b * S * D;
    const u16* qbase = Qb + (size_t)b * S * D;
    const u16* vbase = VTb + (size_t)b * D * S;
    const float* rzb = rzbuf + (size_t)b * S;
    bf16x8 qa0 = *(const bf16x8*)(qbase + (size_t)(i0 + lr) * D + lg * 8);
    bf16x8 qa1 = *(const bf16x8*)(qbase + (size_t)(i0 + lr) * D + 32 + lg * 8);
    f32x4 acc[4] = {};
    int jt_end = min(jc * 4 + 4, it + 1);
    for (int jt = jc * 4; jt < jt_end; ++jt) {
#pragma unroll
      for (int js = 0; js < 4; ++js) {
        int j16 = jt * 64 + js * 16;
        bf16x8 xb0 = *(const bf16x8*)(xbase + (size_t)(j16 + lr) * D + lg * 8);
        bf16x8 xb1 = *(const bf16x8*)(xbase + (size_t)(j16 + lr) * D + 32 + lg * 8);
        f32x4 c = {};
        c = __builtin_amdgcn_mfma_f32_16x16x32_bf16(qa0, xb0, c, 0, 0, 0);
        c = __builtin_amdgcn_mfma_f32_16x16x32_bf16(qa1, xb1, c, 0, 0, 0);
        int j = j16 + lr;
        float rzj = rzb[j];
#pragma unroll
        for (int r = 0; r < 4; ++r) {
          int i = i0 + lg * 4 + r;
          float sc = c[r];
          float wgt = (j <= i && sc > 1.0f) ? __expf(sc * SCL) * rzj : 0.f;
          Plds[w][lg * 4 + r][js * 16 + lr] = f2bf(wgt);
        }
      }
      asm volatile("s_waitcnt lgkmcnt(0)" ::: "memory");
#pragma unroll
      for (int kk = 0; kk < 2; ++kk) {
        bf16x8 pa = *(const bf16x8*)(&Plds[w][lr][kk * 32 + lg * 8]);
#pragma unroll
        for (int dt = 0; dt < 4; ++dt) {
          bf16x8 vbf = *(const bf16x8*)(vbase + (size_t)(dt * 16 + lr) * S + jt * 64 + kk * 32 + lg * 8);
          acc[dt] = __builtin_amdgcn_mfma_f32_16x16x32_bf16(pa, vbf, acc[dt], 0, 0, 0);
        }
      }
      asm volatile("s_waitcnt lgkmcnt(0)" ::: "memory");
    }
    float* obase = out + (size_t)b * S * D;
#pragma unroll
    for (int dt = 0; dt < 4; ++dt)
#pragma unroll
      for (int r = 0; r < 4; ++r) {
        int i = i0 + lg * 4 + r;
        atomicAdd(&obase[(size_t)i * D + dt * 16 + lr], acc[dt][r]);
      }
  }
}

extern "C" void kernel_launch(void* const* d_in, const int* in_sizes, int n_in,
                              void* d_out, int out_size, void* d_ws, size_t ws_size,
                              hipStream_t stream) {
  const float* x  = (const float*)d_in[0];
  const float* wq = (const float*)d_in[1];
  const float* wv = (const float*)d_in[2];
  float* out = (float*)d_out;
  char* ws = (char*)d_ws;
  size_t off = 0;
  auto alloc = [&](size_t bytes) -> void* {
    void* p = ws + off; off += (bytes + 255) & ~255ULL; return p;
  };
  u16* xb   = (u16*)alloc((size_t)BATCH * S * D * 2);
  u16* xTb  = (u16*)alloc((size_t)BATCH * S * D * 2);
  u16* Qb   = (u16*)alloc((size_t)BATCH * S * D * 2);
  u16* VTb  = (u16*)alloc((size_t)BATCH * S * D * 2);
  float* rzbuf = (float*)alloc((size_t)BATCH * S * 4);
  u16* wqp  = (u16*)alloc((size_t)S * S * 2);   // W' = W_Q @ L (suffix-scanned)
  u16* wvb  = (u16*)alloc((size_t)S * S * 2);

  void* args[] = {
    (void*)&x, (void*)&wq, (void*)&wv,
    (void*)&wqp, (void*)&wvb,
    (void*)&xb, (void*)&xTb,
    (void*)&Qb, (void*)&VTb,
    (void*)&rzbuf, (void*)&out
  };
  hipLaunchCooperativeKernel((const void*)k_fused, dim3(NBLK), dim3(256),
                             args, 0, stream);
}

// Round 11
// 75.249 us; speedup vs baseline: 5.3698x; 5.3698x over previous
//
#include <hip/hip_runtime.h>

typedef unsigned short u16;
typedef __bf16 bf16;
typedef bf16 bf16x8 __attribute__((ext_vector_type(8)));
typedef float f32x4 __attribute__((ext_vector_type(4)));

#define S 2048
#define D 64
#define BATCH 4
#define SCL 0.022097086912079612f  /* 1/sqrt(2048) */

__device__ __forceinline__ u16 f2bf(float f) {
  union { float f; unsigned u; } v; v.f = f;
  return (u16)((v.u + 0x7FFFu + ((v.u >> 16) & 1u)) >> 16);
}

__device__ __forceinline__ void gld16(const u16* g, u16* l) {
  __builtin_amdgcn_global_load_lds(
      (const __attribute__((address_space(1))) unsigned int*)(const void*)g,
      (__attribute__((address_space(3))) unsigned int*)(void*)l, 16, 0, 0);
}

// ---- N1: fused pre. Q = W_Q@G == W'@x with W'[m,u] = suffix_{t>=u} W_Q[m,t]/(t+1).
// jobs: [0,512)    W' suffix-scan, 1 wave/row, float4-vectorized, loads prefetched
//       [512,1536) W_V -> bf16 (16 elems/thread)
//       [1536,1664) x -> xb (row-major) + xTb (transposed), bf16
__global__ void k_pre(const float* __restrict__ x,
                      const float* __restrict__ wq, const float* __restrict__ wv,
                      u16* __restrict__ wqp, u16* __restrict__ wvb,
                      u16* __restrict__ xb, u16* __restrict__ xTb) {
  int bx = blockIdx.x, t = threadIdx.x;
  if (bx < 512) {                        // W' suffix scan (vectorized)
    int m = bx * 4 + (t >> 6);
    int l = t & 63;
    const float* row = wq + (size_t)m * S;
    u16* orow = wqp + (size_t)m * S;
    float4 f[8];
#pragma unroll
    for (int c = 0; c < 8; ++c) f[c] = *(const float4*)(row + c * 256 + l * 4);
#pragma unroll
    for (int c = 0; c < 8; ++c) {
      int base = c * 256 + l * 4;
      f[c].x /= (float)(base + 1); f[c].y /= (float)(base + 2);
      f[c].z /= (float)(base + 3); f[c].w /= (float)(base + 4);
    }
    float carry = 0.f;
#pragma unroll
    for (int c = 7; c >= 0; --c) {
      float4 v = f[c];
      float sl = v.x + v.y + v.z + v.w;
      float s = sl;
#pragma unroll
      for (int off = 1; off < 64; off <<= 1) {
        float o = __shfl_down(s, off);
        s += (l + off < 64) ? o : 0.f;
      }
      float tot = __shfl(s, 0);
      float excl = s - sl;               // sum over lanes above
      float s3 = v.w, s2 = v.z + s3, s1 = v.y + s2, s0 = v.x + s1;
      union { u16 q[4]; ushort4 u4; } o;
      o.q[0] = f2bf(carry + excl + s0);
      o.q[1] = f2bf(carry + excl + s1);
      o.q[2] = f2bf(carry + excl + s2);
      o.q[3] = f2bf(carry + excl + s3);
      *(ushort4*)(orow + c * 256 + l * 4) = o.u4;
      carry += tot;
    }
  } else if (bx < 1536) {                // W_V convert, 16 elems/thread
    size_t idx = ((size_t)(bx - 512) * 256 + t) * 16;
#pragma unroll
    for (int h = 0; h < 2; ++h) {
      const float* src = wv + idx + h * 8;
      float4 a = *(const float4*)src;
      float4 b = *(const float4*)(src + 4);
      union { u16 s[8]; uint4 v; } u;
      u.s[0]=f2bf(a.x); u.s[1]=f2bf(a.y); u.s[2]=f2bf(a.z); u.s[3]=f2bf(a.w);
      u.s[4]=f2bf(b.x); u.s[5]=f2bf(b.y); u.s[6]=f2bf(b.z); u.s[7]=f2bf(b.w);
      *(uint4*)(wvb + idx + h * 8) = u.v;
    }
  } else {                               // x convert + transpose
    int job = (bx - 1536) * 4 + (t >> 6);
    int chunk = job >> 2, b = job & 3, d = t & 63;
    const float* xp = x + ((size_t)b * S + (size_t)chunk * 16) * D + d;
#pragma unroll
    for (int s = 0; s < 16; ++s) {
      float v = xp[(size_t)s * D];
      int sg = chunk * 16 + s;
      u16 h = f2bf(v);
      xb[((size_t)b * S + sg) * D + d] = h;
      xTb[((size_t)b * D + d) * S + sg] = h;
    }
  }
}

// ---- N2: GEMMs Q = W'@x, V = W_V@x (shared B-panel xTb). Tile 64M x 32N,
// 128 threads (2 waves x 32Mx32N), BK=128 (16 K-steps), 48 KB LDS,
// 512 blocks = 2/CU. nt-siblings 64 apart (== same XCD mod 8) share panels.
__global__ __launch_bounds__(128) void k_wg(
    const u16* __restrict__ wqp, const u16* __restrict__ wvb,
    const u16* __restrict__ xTb,
    u16* __restrict__ Qb, u16* __restrict__ VTb) {
  __shared__ u16 Ab[2][64 * 128];  // 32 KB
  __shared__ u16 Bb[2][32 * 128];  // 16 KB
  int bx = blockIdx.x;            // nt*64 + mt*2 + mat
  int nt = bx >> 6, mm = bx & 63, mt = mm >> 1, mat = mm & 1;
  int t = threadIdx.x;
  int w = t >> 6, l = t & 63;
  int lr = l & 15, lg = l >> 4;
  const u16* A = (mat ? wvb : wqp) + (size_t)(mt * 64) * S;
  const u16* BT = xTb + (size_t)(nt * 32) * S;
  int rA = t >> 4;                 // 0..7: row within an 8-row issue
  int sb = t & 15;                 // 16B slot within 256B row
  int swz = ((sb & 8) | ((sb & 7) ^ (rA & 7))) * 8;  // pre-swizzled source col
  const u16* Ag = A + (size_t)rA * S + swz;
  const u16* Bg = BT + (size_t)rA * S + swz;
  f32x4 acc[2][2] = {};

  auto stage = [&](int buf, int kt) {
#pragma unroll
    for (int i = 0; i < 8; ++i)
      gld16(Ag + kt * 128 + (size_t)i * 8 * S, &Ab[buf][i * 1024 + t * 8]);
#pragma unroll
    for (int i = 0; i < 4; ++i)
      gld16(Bg + kt * 128 + (size_t)i * 8 * S, &Bb[buf][i * 1024 + t * 8]);
  };

  stage(0, 0);
  __syncthreads();
  int buf = 0;
  for (int kt = 0; kt < 16; ++kt) {
    if (kt < 15) stage(buf ^ 1, kt + 1);
    bf16x8 af[2][4], bfv[2][4];
#pragma unroll
    for (int mf = 0; mf < 2; ++mf)
#pragma unroll
      for (int ks = 0; ks < 4; ++ks) {
        int row = w * 32 + mf * 16 + lr;
        int s = ks * 4 + lg;
        int col = ((s & 8) | ((s & 7) ^ (lr & 7))) * 8;
        af[mf][ks] = *(const bf16x8*)&Ab[buf][row * 128 + col];
      }
#pragma unroll
    for (int nf = 0; nf < 2; ++nf)
#pragma unroll
      for (int ks = 0; ks < 4; ++ks) {
        int row = nf * 16 + lr;
        int s = ks * 4 + lg;
        int col = ((s & 8) | ((s & 7) ^ (lr & 7))) * 8;
        bfv[nf][ks] = *(const bf16x8*)&Bb[buf][row * 128 + col];
      }
#pragma unroll
    for (int ks = 0; ks < 4; ++ks)
#pragma unroll
      for (int mf = 0; mf < 2; ++mf)
#pragma unroll
        for (int nf = 0; nf < 2; ++nf)
          acc[mf][nf] = __builtin_amdgcn_mfma_f32_16x16x32_bf16(af[mf][ks], bfv[nf][ks], acc[mf][nf], 0, 0, 0);
    __syncthreads();
    buf ^= 1;
  }
  // epilogue: m = mt*64 + w*32 + mf*16 + lg*4 + r ; n = nt*32 + nf*16 + lr
#pragma unroll
  for (int mf = 0; mf < 2; ++mf) {
    int mbase = mt * 64 + w * 32 + mf * 16 + lg * 4;
#pragma unroll
    for (int nf = 0; nf < 2; ++nf) {
      int n = nt * 32 + nf * 16 + lr;
      int b = n >> 6, d = n & 63;
      if (mat == 0) {
#pragma unroll
        for (int r = 0; r < 4; ++r)
          Qb[((size_t)b * S + mbase + r) * D + d] = f2bf(acc[mf][nf][r]);
      } else {
        union { u16 s[4]; ushort4 v; } u;
#pragma unroll
        for (int r = 0; r < 4; ++r) u.s[r] = f2bf(acc[mf][nf][r]);
        *(ushort4*)&VTb[((size_t)b * D + d) * S + mbase] = u.v;
      }
    }
  }
}

// ---- N3: column sums Z_j = sum_{i>=j, sc>1} exp(sc*SCL) (no-max: bounded).
// Prologue: each of the 512 blocks zeroes a disjoint 4KB slice of out
// (consumed only by N4, one node later). i-loop unrolled x2 for ILP.
__global__ __launch_bounds__(256) void k_stats(
    const u16* __restrict__ xb, const u16* __restrict__ Qb,
    float* __restrict__ rzbuf, float* __restrict__ out) {
  __shared__ float zs[4][16];
  int jg = blockIdx.x, b = blockIdx.y;
  int tid = threadIdx.x;
  // zero out: block id = b*128+jg owns 1024 floats
  {
    size_t zi = ((size_t)(b * 128 + jg) * 256 + tid) * 4;
    *(float4*)(out + zi) = make_float4(0.f, 0.f, 0.f, 0.f);
  }
  int w = tid >> 6, l = tid & 63;
  int lr = l & 15, lg = l >> 4;
  int j0 = jg * 16;
  const u16* xbase = xb + (size_t)b * S * D;
  const u16* qbase = Qb + (size_t)b * S * D;
  bf16x8 xa0 = *(const bf16x8*)(xbase + (size_t)(j0 + lr) * D + lg * 8);
  bf16x8 xa1 = *(const bf16x8*)(xbase + (size_t)(j0 + lr) * D + 32 + lg * 8);
  float z[4] = {0.f, 0.f, 0.f, 0.f};
  for (int i16 = j0 + w * 16; i16 < S; i16 += 128) {
    // chain 1
    {
      bf16x8 q0 = *(const bf16x8*)(qbase + (size_t)(i16 + lr) * D + lg * 8);
      bf16x8 q1 = *(const bf16x8*)(qbase + (size_t)(i16 + lr) * D + 32 + lg * 8);
      f32x4 c = {};
      c = __builtin_amdgcn_mfma_f32_16x16x32_bf16(xa0, q0, c, 0, 0, 0);
      c = __builtin_amdgcn_mfma_f32_16x16x32_bf16(xa1, q1, c, 0, 0, 0);
      int i = i16 + lr;
#pragma unroll
      for (int r = 0; r < 4; ++r) {
        int j = j0 + lg * 4 + r;
        float sc = c[r];
        z[r] += (i >= j && sc > 1.0f) ? __expf(sc * SCL) : 0.f;
      }
    }
    // chain 2 (independent)
    int i16b = i16 + 64;
    if (i16b < S) {
      bf16x8 q0 = *(const bf16x8*)(qbase + (size_t)(i16b + lr) * D + lg * 8);
      bf16x8 q1 = *(const bf16x8*)(qbase + (size_t)(i16b + lr) * D + 32 + lg * 8);
      f32x4 c = {};
      c = __builtin_amdgcn_mfma_f32_16x16x32_bf16(xa0, q0, c, 0, 0, 0);
      c = __builtin_amdgcn_mfma_f32_16x16x32_bf16(xa1, q1, c, 0, 0, 0);
      int i = i16b + lr;
#pragma unroll
      for (int r = 0; r < 4; ++r) {
        int j = j0 + lg * 4 + r;
        float sc = c[r];
        z[r] += (i >= j && sc > 1.0f) ? __expf(sc * SCL) : 0.f;
      }
    }
  }
#pragma unroll
  for (int r = 0; r < 4; ++r) {
    z[r] += __shfl_xor(z[r], 1);
    z[r] += __shfl_xor(z[r], 2);
    z[r] += __shfl_xor(z[r], 4);
    z[r] += __shfl_xor(z[r], 8);
  }
  if (lr == 0) {
#pragma unroll
    for (int r = 0; r < 4; ++r) zs[w][lg * 4 + r] = z[r];
  }
  __syncthreads();
  if (tid < 16) {
    float zf = zs[0][tid] + zs[1][tid] + zs[2][tid] + zs[3][tid];
    rzbuf[(size_t)b * S + j0 + tid] = 1.0f / zf;
  }
}

// ---- N4: out += P_chunk @ V_chunk; P_ij = exp(sc*SCL)/Z_j (or 0).
// Reversed decode: heavy i-tiles dispatch first.
__global__ __launch_bounds__(256) void k_out(
    const u16* __restrict__ xb, const u16* __restrict__ Qb, const u16* __restrict__ VTb,
    const float* __restrict__ rzbuf, float* __restrict__ out) {
  __shared__ u16 Plds[4][16][72];
  int bx = 143 - blockIdx.x, b = blockIdx.y;   // heavy-first
  int it = 0, jc = 0, base = 0;
  for (int tt = 0; tt < 32; ++tt) {
    int nc = (tt + 4) >> 2;
    if (bx < base + nc) { it = tt; jc = bx - base; break; }
    base += nc;
  }
  int w = threadIdx.x >> 6, l = threadIdx.x & 63;
  int lr = l & 15, lg = l >> 4;
  int i0 = it * 64 + w * 16;
  const u16* xbase = xb + (size_t)b * S * D;
  const u16* qbase = Qb + (size_t)b * S * D;
  const u16* vbase = VTb + (size_t)b * D * S;
  const float* rzb = rzbuf + (size_t)b * S;
  bf16x8 qa0 = *(const bf16x8*)(qbase + (size_t)(i0 + lr) * D + lg * 8);
  bf16x8 qa1 = *(const bf16x8*)(qbase + (size_t)(i0 + lr) * D + 32 + lg * 8);
  f32x4 acc[4] = {};
  int jt_end = min(jc * 4 + 4, it + 1);
  for (int jt = jc * 4; jt < jt_end; ++jt) {
#pragma unroll
    for (int js = 0; js < 4; ++js) {
      int j16 = jt * 64 + js * 16;
      bf16x8 xb0 = *(const bf16x8*)(xbase + (size_t)(j16 + lr) * D + lg * 8);
      bf16x8 xb1 = *(const bf16x8*)(xbase + (size_t)(j16 + lr) * D + 32 + lg * 8);
      f32x4 c = {};
      c = __builtin_amdgcn_mfma_f32_16x16x32_bf16(qa0, xb0, c, 0, 0, 0);
      c = __builtin_amdgcn_mfma_f32_16x16x32_bf16(qa1, xb1, c, 0, 0, 0);
      int j = j16 + lr;
      float rzj = rzb[j];
#pragma unroll
      for (int r = 0; r < 4; ++r) {
        int i = i0 + lg * 4 + r;
        float sc = c[r];
        float wgt = (j <= i && sc > 1.0f) ? __expf(sc * SCL) * rzj : 0.f;
        Plds[w][lg * 4 + r][js * 16 + lr] = f2bf(wgt);
      }
    }
    asm volatile("s_waitcnt lgkmcnt(0)" ::: "memory");
#pragma unroll
    for (int kk = 0; kk < 2; ++kk) {
      bf16x8 pa = *(const bf16x8*)(&Plds[w][lr][kk * 32 + lg * 8]);
#pragma unroll
      for (int dt = 0; dt < 4; ++dt) {
        bf16x8 vbf = *(const bf16x8*)(vbase + (size_t)(dt * 16 + lr) * S + jt * 64 + kk * 32 + lg * 8);
        acc[dt] = __builtin_amdgcn_mfma_f32_16x16x32_bf16(pa, vbf, acc[dt], 0, 0, 0);
      }
    }
    asm volatile("s_waitcnt lgkmcnt(0)" ::: "memory");
  }
  float* obase = out + (size_t)b * S * D;
#pragma unroll
  for (int dt = 0; dt < 4; ++dt)
#pragma unroll
    for (int r = 0; r < 4; ++r) {
      int i = i0 + lg * 4 + r;
      atomicAdd(&obase[(size_t)i * D + dt * 16 + lr], acc[dt][r]);
    }
}

extern "C" void kernel_launch(void* const* d_in, const int* in_sizes, int n_in,
                              void* d_out, int out_size, void* d_ws, size_t ws_size,
                              hipStream_t stream) {
  const float* x  = (const float*)d_in[0];
  const float* wq = (const float*)d_in[1];
  const float* wv = (const float*)d_in[2];
  float* out = (float*)d_out;
  char* ws = (char*)d_ws;
  size_t off = 0;
  auto alloc = [&](size_t bytes) -> void* {
    void* p = ws + off; off += (bytes + 255) & ~255ULL; return p;
  };
  u16* xb   = (u16*)alloc((size_t)BATCH * S * D * 2);
  u16* xTb  = (u16*)alloc((size_t)BATCH * S * D * 2);
  u16* Qb   = (u16*)alloc((size_t)BATCH * S * D * 2);
  u16* VTb  = (u16*)alloc((size_t)BATCH * S * D * 2);
  float* rzbuf = (float*)alloc((size_t)BATCH * S * 4);
  u16* wqp  = (u16*)alloc((size_t)S * S * 2);   // W' = W_Q @ L (suffix-scanned)
  u16* wvb  = (u16*)alloc((size_t)S * S * 2);

  k_pre<<<1664, 256, 0, stream>>>(x, wq, wv, wqp, wvb, xb, xTb);
  k_wg<<<512, 128, 0, stream>>>(wqp, wvb, xTb, Qb, VTb);
  k_stats<<<dim3(128, BATCH), 256, 0, stream>>>(xb, Qb, rzbuf, out);
  k_out<<<dim3(144, BATCH), 256, 0, stream>>>(xb, Qb, VTb, rzbuf, out);
}

// Round 12
// 72.198 us; speedup vs baseline: 5.5968x; 1.0423x over previous
//
#include <hip/hip_runtime.h>

typedef unsigned short u16;
typedef __bf16 bf16;
typedef bf16 bf16x8 __attribute__((ext_vector_type(8)));
typedef float f32x4 __attribute__((ext_vector_type(4)));

#define S 2048
#define D 64
#define BATCH 4
#define SCL 0.022097086912079612f  /* 1/sqrt(2048) */

__device__ __forceinline__ u16 f2bf(float f) {
  union { float f; unsigned u; } v; v.f = f;
  return (u16)((v.u + 0x7FFFu + ((v.u >> 16) & 1u)) >> 16);
}

__device__ __forceinline__ void gld16(const u16* g, u16* l) {
  __builtin_amdgcn_global_load_lds(
      (const __attribute__((address_space(1))) unsigned int*)(const void*)g,
      (__attribute__((address_space(3))) unsigned int*)(void*)l, 16, 0, 0);
}

// ---- N1: fused pre. Q = W_Q@G == W'@x with W'[m,u] = suffix_{t>=u} W_Q[m,t]/(t+1).
__global__ void k_pre(const float* __restrict__ x,
                      const float* __restrict__ wq, const float* __restrict__ wv,
                      u16* __restrict__ wqp, u16* __restrict__ wvb,
                      u16* __restrict__ xb, u16* __restrict__ xTb) {
  int bx = blockIdx.x, t = threadIdx.x;
  if (bx < 512) {                        // W' suffix scan (vectorized)
    int m = bx * 4 + (t >> 6);
    int l = t & 63;
    const float* row = wq + (size_t)m * S;
    u16* orow = wqp + (size_t)m * S;
    float4 f[8];
#pragma unroll
    for (int c = 0; c < 8; ++c) f[c] = *(const float4*)(row + c * 256 + l * 4);
#pragma unroll
    for (int c = 0; c < 8; ++c) {
      int base = c * 256 + l * 4;
      f[c].x /= (float)(base + 1); f[c].y /= (float)(base + 2);
      f[c].z /= (float)(base + 3); f[c].w /= (float)(base + 4);
    }
    float carry = 0.f;
#pragma unroll
    for (int c = 7; c >= 0; --c) {
      float4 v = f[c];
      float sl = v.x + v.y + v.z + v.w;
      float s = sl;
#pragma unroll
      for (int off = 1; off < 64; off <<= 1) {
        float o = __shfl_down(s, off);
        s += (l + off < 64) ? o : 0.f;
      }
      float tot = __shfl(s, 0);
      float excl = s - sl;               // sum over lanes above
      float s3 = v.w, s2 = v.z + s3, s1 = v.y + s2, s0 = v.x + s1;
      union { u16 q[4]; ushort4 u4; } o;
      o.q[0] = f2bf(carry + excl + s0);
      o.q[1] = f2bf(carry + excl + s1);
      o.q[2] = f2bf(carry + excl + s2);
      o.q[3] = f2bf(carry + excl + s3);
      *(ushort4*)(orow + c * 256 + l * 4) = o.u4;
      carry += tot;
    }
  } else if (bx < 1536) {                // W_V convert, 16 elems/thread
    size_t idx = ((size_t)(bx - 512) * 256 + t) * 16;
#pragma unroll
    for (int h = 0; h < 2; ++h) {
      const float* src = wv + idx + h * 8;
      float4 a = *(const float4*)src;
      float4 b = *(const float4*)(src + 4);
      union { u16 s[8]; uint4 v; } u;
      u.s[0]=f2bf(a.x); u.s[1]=f2bf(a.y); u.s[2]=f2bf(a.z); u.s[3]=f2bf(a.w);
      u.s[4]=f2bf(b.x); u.s[5]=f2bf(b.y); u.s[6]=f2bf(b.z); u.s[7]=f2bf(b.w);
      *(uint4*)(wvb + idx + h * 8) = u.v;
    }
  } else {                               // x convert + transpose
    int job = (bx - 1536) * 4 + (t >> 6);
    int chunk = job >> 2, b = job & 3, d = t & 63;
    const float* xp = x + ((size_t)b * S + (size_t)chunk * 16) * D + d;
#pragma unroll
    for (int s = 0; s < 16; ++s) {
      float v = xp[(size_t)s * D];
      int sg = chunk * 16 + s;
      u16 h = f2bf(v);
      xb[((size_t)b * S + sg) * D + d] = h;
      xTb[((size_t)b * D + d) * S + sg] = h;
    }
  }
}

// ---- N2: GEMMs Q = W'@x, V = W_V@x (shared B-panel xTb). Tile 32M x 32N,
// BK=128 (16 K-steps), 128 threads (2 waves x 16Mx32N), 32 KB LDS,
// 1024 blocks = 4/CU (2 waves/SIMD). bx = nt*128+mg keeps all nt-siblings
// of an A-panel on one XCD (bx%8 == mg%8) -> A refetch is L2-local.
__global__ __launch_bounds__(128) void k_wg(
    const u16* __restrict__ wqp, const u16* __restrict__ wvb,
    const u16* __restrict__ xTb,
    u16* __restrict__ Qb, u16* __restrict__ VTb) {
  __shared__ u16 Ab[2][32 * 128];  // 16 KB
  __shared__ u16 Bb[2][32 * 128];  // 16 KB
  int bx = blockIdx.x;
  int nt = bx >> 7, mg = bx & 127;
  int mat = mg >> 6;               // rows 0..2047 -> wqp, 2048..4095 -> wvb
  int mrow = (mg & 63) * 32;
  int t = threadIdx.x;
  int w = t >> 6, l = t & 63;
  int lr = l & 15, lg = l >> 4;
  const u16* A = (mat ? wvb : wqp) + (size_t)mrow * S;
  const u16* BT = xTb + (size_t)(nt * 32) * S;
  int rA = t >> 4;                 // 0..7: row within an 8-row issue
  int sb = t & 15;                 // 16B slot within 256B row
  int swz = ((sb & 8) | ((sb & 7) ^ (rA & 7))) * 8;  // pre-swizzled source col
  const u16* Ag = A + (size_t)rA * S + swz;
  const u16* Bg = BT + (size_t)rA * S + swz;
  f32x4 acc[2] = {};

  auto stage = [&](int buf, int kt) {
#pragma unroll
    for (int i = 0; i < 4; ++i)
      gld16(Ag + kt * 128 + (size_t)i * 8 * S, &Ab[buf][i * 1024 + t * 8]);
#pragma unroll
    for (int i = 0; i < 4; ++i)
      gld16(Bg + kt * 128 + (size_t)i * 8 * S, &Bb[buf][i * 1024 + t * 8]);
  };

  stage(0, 0);
  __syncthreads();
  int buf = 0;
  for (int kt = 0; kt < 16; ++kt) {
    if (kt < 15) stage(buf ^ 1, kt + 1);
    bf16x8 af[4], bfv[2][4];
#pragma unroll
    for (int ks = 0; ks < 4; ++ks) {
      int row = w * 16 + lr;
      int s = ks * 4 + lg;
      int col = ((s & 8) | ((s & 7) ^ (lr & 7))) * 8;
      af[ks] = *(const bf16x8*)&Ab[buf][row * 128 + col];
    }
#pragma unroll
    for (int nf = 0; nf < 2; ++nf)
#pragma unroll
      for (int ks = 0; ks < 4; ++ks) {
        int row = nf * 16 + lr;
        int s = ks * 4 + lg;
        int col = ((s & 8) | ((s & 7) ^ (lr & 7))) * 8;
        bfv[nf][ks] = *(const bf16x8*)&Bb[buf][row * 128 + col];
      }
#pragma unroll
    for (int ks = 0; ks < 4; ++ks)
#pragma unroll
      for (int nf = 0; nf < 2; ++nf)
        acc[nf] = __builtin_amdgcn_mfma_f32_16x16x32_bf16(af[ks], bfv[nf][ks], acc[nf], 0, 0, 0);
    __syncthreads();
    buf ^= 1;
  }
  // epilogue: m(in-mat) = mrow + w*16 + lg*4 + r ; n = nt*32 + nf*16 + lr
  int mbase = mrow + w * 16 + lg * 4;
#pragma unroll
  for (int nf = 0; nf < 2; ++nf) {
    int n = nt * 32 + nf * 16 + lr;
    int b = n >> 6, d = n & 63;
    if (mat == 0) {
#pragma unroll
      for (int r = 0; r < 4; ++r)
        Qb[((size_t)b * S + mbase + r) * D + d] = f2bf(acc[nf][r]);
    } else {
      union { u16 s[4]; ushort4 v; } u;
#pragma unroll
      for (int r = 0; r < 4; ++r) u.s[r] = f2bf(acc[nf][r]);
      *(ushort4*)&VTb[((size_t)b * D + d) * S + mbase] = u.v;
    }
  }
}

// ---- N3: column sums Z_j = sum_{i>=j, sc>1} exp(sc*SCL) (no-max: bounded).
// Prologue zeroes a disjoint slice of out. i-loop unrolled x2 for ILP.
__global__ __launch_bounds__(256) void k_stats(
    const u16* __restrict__ xb, const u16* __restrict__ Qb,
    float* __restrict__ rzbuf, float* __restrict__ out) {
  __shared__ float zs[4][16];
  int jg = blockIdx.x, b = blockIdx.y;
  int tid = threadIdx.x;
  {
    size_t zi = ((size_t)(b * 128 + jg) * 256 + tid) * 4;
    *(float4*)(out + zi) = make_float4(0.f, 0.f, 0.f, 0.f);
  }
  int w = tid >> 6, l = tid & 63;
  int lr = l & 15, lg = l >> 4;
  int j0 = jg * 16;
  const u16* xbase = xb + (size_t)b * S * D;
  const u16* qbase = Qb + (size_t)b * S * D;
  bf16x8 xa0 = *(const bf16x8*)(xbase + (size_t)(j0 + lr) * D + lg * 8);
  bf16x8 xa1 = *(const bf16x8*)(xbase + (size_t)(j0 + lr) * D + 32 + lg * 8);
  float z[4] = {0.f, 0.f, 0.f, 0.f};
  for (int i16 = j0 + w * 16; i16 < S; i16 += 128) {
    {
      bf16x8 q0 = *(const bf16x8*)(qbase + (size_t)(i16 + lr) * D + lg * 8);
      bf16x8 q1 = *(const bf16x8*)(qbase + (size_t)(i16 + lr) * D + 32 + lg * 8);
      f32x4 c = {};
      c = __builtin_amdgcn_mfma_f32_16x16x32_bf16(xa0, q0, c, 0, 0, 0);
      c = __builtin_amdgcn_mfma_f32_16x16x32_bf16(xa1, q1, c, 0, 0, 0);
      int i = i16 + lr;
#pragma unroll
      for (int r = 0; r < 4; ++r) {
        int j = j0 + lg * 4 + r;
        float sc = c[r];
        z[r] += (i >= j && sc > 1.0f) ? __expf(sc * SCL) : 0.f;
      }
    }
    int i16b = i16 + 64;
    if (i16b < S) {
      bf16x8 q0 = *(const bf16x8*)(qbase + (size_t)(i16b + lr) * D + lg * 8);
      bf16x8 q1 = *(const bf16x8*)(qbase + (size_t)(i16b + lr) * D + 32 + lg * 8);
      f32x4 c = {};
      c = __builtin_amdgcn_mfma_f32_16x16x32_bf16(xa0, q0, c, 0, 0, 0);
      c = __builtin_amdgcn_mfma_f32_16x16x32_bf16(xa1, q1, c, 0, 0, 0);
      int i = i16b + lr;
#pragma unroll
      for (int r = 0; r < 4; ++r) {
        int j = j0 + lg * 4 + r;
        float sc = c[r];
        z[r] += (i >= j && sc > 1.0f) ? __expf(sc * SCL) : 0.f;
      }
    }
  }
#pragma unroll
  for (int r = 0; r < 4; ++r) {
    z[r] += __shfl_xor(z[r], 1);
    z[r] += __shfl_xor(z[r], 2);
    z[r] += __shfl_xor(z[r], 4);
    z[r] += __shfl_xor(z[r], 8);
  }
  if (lr == 0) {
#pragma unroll
    for (int r = 0; r < 4; ++r) zs[w][lg * 4 + r] = z[r];
  }
  __syncthreads();
  if (tid < 16) {
    float zf = zs[0][tid] + zs[1][tid] + zs[2][tid] + zs[3][tid];
    rzbuf[(size_t)b * S + j0 + tid] = 1.0f / zf;
  }
}

// ---- N4: out += P_chunk @ V_chunk; P_ij = exp(sc*SCL)/Z_j (or 0).
// Heavy-first decode; setprio around the pure-MFMA PV cluster (independent
// barrier-free blocks -> wave phase diversity, the regime where it helps).
__global__ __launch_bounds__(256) void k_out(
    const u16* __restrict__ xb, const u16* __restrict__ Qb, const u16* __restrict__ VTb,
    const float* __restrict__ rzbuf, float* __restrict__ out) {
  __shared__ u16 Plds[4][16][72];
  int bx = 143 - blockIdx.x, b = blockIdx.y;   // heavy-first
  int it = 0, jc = 0, base = 0;
  for (int tt = 0; tt < 32; ++tt) {
    int nc = (tt + 4) >> 2;
    if (bx < base + nc) { it = tt; jc = bx - base; break; }
    base += nc;
  }
  int w = threadIdx.x >> 6, l = threadIdx.x & 63;
  int lr = l & 15, lg = l >> 4;
  int i0 = it * 64 + w * 16;
  const u16* xbase = xb + (size_t)b * S * D;
  const u16* qbase = Qb + (size_t)b * S * D;
  const u16* vbase = VTb + (size_t)b * D * S;
  const float* rzb = rzbuf + (size_t)b * S;
  bf16x8 qa0 = *(const bf16x8*)(qbase + (size_t)(i0 + lr) * D + lg * 8);
  bf16x8 qa1 = *(const bf16x8*)(qbase + (size_t)(i0 + lr) * D + 32 + lg * 8);
  f32x4 acc[4] = {};
  int jt_end = min(jc * 4 + 4, it + 1);
  for (int jt = jc * 4; jt < jt_end; ++jt) {
#pragma unroll
    for (int js = 0; js < 4; ++js) {
      int j16 = jt * 64 + js * 16;
      bf16x8 xb0 = *(const bf16x8*)(xbase + (size_t)(j16 + lr) * D + lg * 8);
      bf16x8 xb1 = *(const bf16x8*)(xbase + (size_t)(j16 + lr) * D + 32 + lg * 8);
      f32x4 c = {};
      c = __builtin_amdgcn_mfma_f32_16x16x32_bf16(qa0, xb0, c, 0, 0, 0);
      c = __builtin_amdgcn_mfma_f32_16x16x32_bf16(qa1, xb1, c, 0, 0, 0);
      int j = j16 + lr;
      float rzj = rzb[j];
#pragma unroll
      for (int r = 0; r < 4; ++r) {
        int i = i0 + lg * 4 + r;
        float sc = c[r];
        float wgt = (j <= i && sc > 1.0f) ? __expf(sc * SCL) * rzj : 0.f;
        Plds[w][lg * 4 + r][js * 16 + lr] = f2bf(wgt);
      }
    }
    asm volatile("s_waitcnt lgkmcnt(0)" ::: "memory");
    __builtin_amdgcn_s_setprio(1);
#pragma unroll
    for (int kk = 0; kk < 2; ++kk) {
      bf16x8 pa = *(const bf16x8*)(&Plds[w][lr][kk * 32 + lg * 8]);
#pragma unroll
      for (int dt = 0; dt < 4; ++dt) {
        bf16x8 vbf = *(const bf16x8*)(vbase + (size_t)(dt * 16 + lr) * S + jt * 64 + kk * 32 + lg * 8);
        acc[dt] = __builtin_amdgcn_mfma_f32_16x16x32_bf16(pa, vbf, acc[dt], 0, 0, 0);
      }
    }
    __builtin_amdgcn_s_setprio(0);
    asm volatile("s_waitcnt lgkmcnt(0)" ::: "memory");
  }
  float* obase = out + (size_t)b * S * D;
#pragma unroll
  for (int dt = 0; dt < 4; ++dt)
#pragma unroll
    for (int r = 0; r < 4; ++r) {
      int i = i0 + lg * 4 + r;
      atomicAdd(&obase[(size_t)i * D + dt * 16 + lr], acc[dt][r]);
    }
}

extern "C" void kernel_launch(void* const* d_in, const int* in_sizes, int n_in,
                              void* d_out, int out_size, void* d_ws, size_t ws_size,
                              hipStream_t stream) {
  const float* x  = (const float*)d_in[0];
  const float* wq = (const float*)d_in[1];
  const float* wv = (const float*)d_in[2];
  float* out = (float*)d_out;
  char* ws = (char*)d_ws;
  size_t off = 0;
  auto alloc = [&](size_t bytes) -> void* {
    void* p = ws + off; off += (bytes + 255) & ~255ULL; return p;
  };
  u16* xb   = (u16*)alloc((size_t)BATCH * S * D * 2);
  u16* xTb  = (u16*)alloc((size_t)BATCH * S * D * 2);
  u16* Qb   = (u16*)alloc((size_t)BATCH * S * D * 2);
  u16* VTb  = (u16*)alloc((size_t)BATCH * S * D * 2);
  float* rzbuf = (float*)alloc((size_t)BATCH * S * 4);
  u16* wqp  = (u16*)alloc((size_t)S * S * 2);   // W' = W_Q @ L (suffix-scanned)
  u16* wvb  = (u16*)alloc((size_t)S * S * 2);

  k_pre<<<1664, 256, 0, stream>>>(x, wq, wv, wqp, wvb, xb, xTb);
  k_wg<<<1024, 128, 0, stream>>>(wqp, wvb, xTb, Qb, VTb);
  k_stats<<<dim3(128, BATCH), 256, 0, stream>>>(xb, Qb, rzbuf, out);
  k_out<<<dim3(144, BATCH), 256, 0, stream>>>(xb, Qb, VTb, rzbuf, out);
}